// Round 1
// baseline (278.930 us; speedup 1.0000x reference)
//
#include <hip/hip_runtime.h>
#include <hip/hip_bf16.h>

// Problem constants (fixed by the reference):
//   img [8192,1024] f32, txt [8192,1024] f32, both l2-normalized
//   set sizes si=st=4, t=16, tts=1, DENOM=2  -> out[bi][bt] = (right+left)/128
//   out [2048,2048] f32
#define N_ROWS 8192
#define DIM    1024
#define BOUT   2048
#define BM 128
#define BN 128
#define BK 32

typedef unsigned short u16;
typedef __attribute__((ext_vector_type(4))) unsigned short u16x4;
typedef __attribute__((ext_vector_type(8))) short short8;   // 8 bf16 (4 VGPRs) MFMA A/B frag
typedef __attribute__((ext_vector_type(4))) float f32x4;    // MFMA C/D frag

// fp32 -> bf16 round-to-nearest-even
__device__ __forceinline__ u16 f2bf(float f) {
  unsigned u = __float_as_uint(f);
  u += 0x7fffu + ((u >> 16) & 1u);
  return (u16)(u >> 16);
}

__global__ void cast_kernel(const float* __restrict__ a, const float* __restrict__ b,
                            u16* __restrict__ oa, u16* __restrict__ ob) {
  const size_t i = ((size_t)blockIdx.x * 256 + threadIdx.x) * 4;
  float4 va = *reinterpret_cast<const float4*>(a + i);
  float4 vb = *reinterpret_cast<const float4*>(b + i);
  u16x4 ua, ub;
  ua[0] = f2bf(va.x); ua[1] = f2bf(va.y); ua[2] = f2bf(va.z); ua[3] = f2bf(va.w);
  ub[0] = f2bf(vb.x); ub[1] = f2bf(vb.y); ub[2] = f2bf(vb.z); ub[3] = f2bf(vb.w);
  *reinterpret_cast<u16x4*>(oa + i) = ua;
  *reinterpret_cast<u16x4*>(ob + i) = ub;
}

// async 16B global->LDS copy (wave-uniform LDS base + lane*16 — layout must be
// contiguous in lane order; our staging mapping guarantees this, no padding)
__device__ __forceinline__ void async_cp16(const u16* g, u16* l) {
  __builtin_amdgcn_global_load_lds(
      (const __attribute__((address_space(1))) void*)g,
      (__attribute__((address_space(3))) void*)l, 16, 0, 0);
}

// NT GEMM (A [M,K] row-major, B [N,K] row-major, dist = A.B^T) with fused
// smooth-chamfer 4x4-block reduction epilogue. m97-style structure:
// 128x128 block tile, 4 waves (2x2), each wave 4x4 tiles of 16x16x32 MFMA.
__global__ __launch_bounds__(256) void gemm_chamfer(
    const u16* __restrict__ A, const u16* __restrict__ B, float* __restrict__ out) {
  __shared__ __align__(16) u16 lA[BM * BK];   // 8 KiB
  __shared__ __align__(16) u16 lB[BN * BK];   // 8 KiB

  const int tid  = threadIdx.x;
  const int lane = tid & 63;
  const int wave = tid >> 6;
  const int wm = wave & 1;          // wave row (64 rows)
  const int wn = wave >> 1;         // wave col (64 cols)
  const int bm0 = blockIdx.x * BM;
  const int bn0 = blockIdx.y * BN;

  // staging map: thread t -> row t>>2 (and +64), 8-elem k-chunk (t&3)*8
  // LDS byte offset = wave*1024 + lane*16  (wave-uniform base + lane*16) ✓
  const int ldrow = tid >> 2;
  const int ldk   = (tid & 3) * 8;
  const u16* aSrc = A + (size_t)(bm0 + ldrow) * DIM + ldk;
  const u16* bSrc = B + (size_t)(bn0 + ldrow) * DIM + ldk;
  u16* aDst = &lA[ldrow * BK + ldk];
  u16* bDst = &lB[ldrow * BK + ldk];
  const size_t half = (size_t)64 * DIM;

  f32x4 acc[4][4] = {};

  const int lm = lane & 15;   // A row / B row (=C col) within 16-tile
  const int lq = lane >> 4;   // k-quad for A/B frags; row-quad for C

  for (int k = 0; k < DIM; k += BK) {
    async_cp16(aSrc + k,        aDst);
    async_cp16(aSrc + k + half, aDst + 64 * BK);
    async_cp16(bSrc + k,        bDst);
    async_cp16(bSrc + k + half, bDst + 64 * BK);
    __syncthreads();   // compiler emits s_waitcnt vmcnt(0) before s_barrier

    short8 af[4], bfv[4];
#pragma unroll
    for (int mt = 0; mt < 4; ++mt)
      af[mt] = *reinterpret_cast<const short8*>(&lA[(wm * 64 + mt * 16 + lm) * BK + lq * 8]);
#pragma unroll
    for (int nt = 0; nt < 4; ++nt)
      bfv[nt] = *reinterpret_cast<const short8*>(&lB[(wn * 64 + nt * 16 + lm) * BK + lq * 8]);

#pragma unroll
    for (int mt = 0; mt < 4; ++mt)
#pragma unroll
      for (int nt = 0; nt < 4; ++nt)
        acc[mt][nt] = __builtin_amdgcn_mfma_f32_16x16x32_bf16(af[mt], bfv[nt], acc[mt][nt], 0, 0, 0);
    __syncthreads();
  }

  // Fused epilogue. C layout: col = lane&15, row = lq*4 + reg — each lane's
  // 4 regs are one full img-set (4 rows) of one column. Set blocks are
  // 4-aligned in both dims, so cross-col sums are shfl_xor over lanes 1,2.
#pragma unroll
  for (int mt = 0; mt < 4; ++mt) {
#pragma unroll
    for (int nt = 0; nt < 4; ++nt) {
      f32x4 c = acc[mt][nt];
      float e0 = __expf(16.0f * c[0]);
      float e1 = __expf(16.0f * c[1]);
      float e2 = __expf(16.0f * c[2]);
      float e3 = __expf(16.0f * c[3]);
      // left partial: log of sum over the 4 img-set rows (in-lane), per column
      float l = __logf(e0 + e1 + e2 + e3);
      // right: per-row sums over the 4 txt-set columns (cross-lane)
      e0 += __shfl_xor(e0, 1); e0 += __shfl_xor(e0, 2);
      e1 += __shfl_xor(e1, 1); e1 += __shfl_xor(e1, 2);
      e2 += __shfl_xor(e2, 1); e2 += __shfl_xor(e2, 2);
      e3 += __shfl_xor(e3, 1); e3 += __shfl_xor(e3, 2);
      float r = __logf(e0) + __logf(e1) + __logf(e2) + __logf(e3);
      // left: sum the per-column logs over the 4 txt-set columns
      l += __shfl_xor(l, 1); l += __shfl_xor(l, 2);
      if ((lane & 3) == 0) {
        const int obi = ((bm0 + wm * 64 + mt * 16) >> 2) + lq;
        const int obt = ((bn0 + wn * 64 + nt * 16) >> 2) + (lm >> 2);
        out[(size_t)obi * BOUT + obt] = (r + l) * 0.0078125f;  // /128
      }
    }
  }
}

extern "C" void kernel_launch(void* const* d_in, const int* in_sizes, int n_in,
                              void* d_out, int out_size, void* d_ws, size_t ws_size,
                              hipStream_t stream) {
  const float* img = (const float*)d_in[0];
  const float* txt = (const float*)d_in[1];
  float* out = (float*)d_out;
  u16* bA = (u16*)d_ws;                       // 16 MiB
  u16* bB = bA + (size_t)N_ROWS * DIM;        // 16 MiB

  const int nPer = N_ROWS * DIM;              // 8388608 per input
  cast_kernel<<<dim3(nPer / (256 * 4)), dim3(256), 0, stream>>>(img, txt, bA, bB);

  dim3 ggrid(N_ROWS / BM, N_ROWS / BN);       // 64 x 64 = 4096 blocks
  gemm_chamfer<<<ggrid, dim3(256), 0, stream>>>(bA, bB, out);
}